// Round 1
// baseline (647.831 us; speedup 1.0000x reference)
//
#include <hip/hip_runtime.h>

#define DD 2048
#define HH 512
#define MT 64      // tokens per block
#define BK 64      // K-tile
#define NTOK 16384 // B*S

typedef __attribute__((ext_vector_type(8))) short short8_t;
typedef __attribute__((ext_vector_type(4))) short short4_t;
typedef __attribute__((ext_vector_type(4))) float f32x4;

static __device__ __forceinline__ short f2bf(float f) {
    union { float f; unsigned u; } v; v.f = f;
    unsigned r = (v.u + 0x7fffu + ((v.u >> 16) & 1u)) >> 16;
    return (short)r;
}

// ---------------- weight fp32 -> bf16 ----------------
__global__ __launch_bounds__(256) void k_cvt(const float* __restrict__ wd,
                                             const float* __restrict__ wu,
                                             short* __restrict__ wdo,
                                             short* __restrict__ wuo) {
    int i = (blockIdx.x * 256 + threadIdx.x) * 4;  // 1048576 elems each
    float4 a = *(const float4*)(wd + i);
    float4 b = *(const float4*)(wu + i);
    short4_t sa, sb;
    sa[0] = f2bf(a.x); sa[1] = f2bf(a.y); sa[2] = f2bf(a.z); sa[3] = f2bf(a.w);
    sb[0] = f2bf(b.x); sb[1] = f2bf(b.y); sb[2] = f2bf(b.z); sb[3] = f2bf(b.w);
    *(short4_t*)(wdo + i) = sa;
    *(short4_t*)(wuo + i) = sb;
}

// ---------------- LN + down-proj + ReLU -> hidden bf16 ----------------
__global__ __launch_bounds__(512, 2) void k_ln_down(
    const float* __restrict__ x, const float* __restrict__ gamma,
    const float* __restrict__ beta, const float* __restrict__ b_down,
    const short* __restrict__ Wd,   // bf16 [H][D], K(=d) contiguous
    short* __restrict__ hid)        // bf16 [NTOK][H]
{
    __shared__ __align__(16) short s_xn[MT * BK];   // swizzled tile
    __shared__ float s_mu[MT], s_rs[MT];

    const int tid  = threadIdx.x;
    const int lane = tid & 63;
    const int w    = tid >> 6;           // 0..7
    const int tok0 = blockIdx.x * MT;

    // phase 1: LN stats; wave w handles local tokens 8w..8w+7, 8 lanes/token
    {
        int tl = w * 8 + (lane >> 3);
        int s  = lane & 7;
        const float* xr = x + (size_t)(tok0 + tl) * DD;
        float sum = 0.f, sq = 0.f;
        for (int i = 0; i < DD / 32; i++) {
            float4 v = *(const float4*)(xr + i * 32 + s * 4);
            sum += v.x + v.y + v.z + v.w;
            sq  += v.x * v.x + v.y * v.y + v.z * v.z + v.w * v.w;
        }
        for (int m = 1; m < 8; m <<= 1) {
            sum += __shfl_xor(sum, m);
            sq  += __shfl_xor(sq, m);
        }
        if (s == 0) {
            float mu  = sum * (1.f / DD);
            float var = sq * (1.f / DD) - mu * mu;
            s_mu[tl] = mu;
            s_rs[tl] = rsqrtf(var + 1e-5f);
        }
    }
    __syncthreads();

    // staging identity: each thread owns (row, 16B chunk)
    const int srow   = tid >> 3;   // 0..63
    const int schunk = tid & 7;    // 0..7
    const float mu = s_mu[srow], rs = s_rs[srow];
    const float* xrow = x + (size_t)(tok0 + srow) * DD;

    // wave tile: wm in 0..3 picks 16 token rows, wh in 0..1 picks 256 h cols
    const int wm = w >> 1, wh = w & 1;
    const int arow = wm * 16 + (lane & 15);
    const int kgrp = lane >> 4;          // 0..3

    f32x4 acc[16];
#pragma unroll
    for (int i = 0; i < 16; i++) acc[i] = (f32x4){0.f, 0.f, 0.f, 0.f};

    for (int kb = 0; kb < DD; kb += BK) {
        // stage normalized bf16 tile (XOR-swizzled 16B chunks)
        {
            const float* p = xrow + kb + schunk * 8;
            float4 v0 = *(const float4*)(p);
            float4 v1 = *(const float4*)(p + 4);
            float4 g0 = *(const float4*)(gamma + kb + schunk * 8);
            float4 g1 = *(const float4*)(gamma + kb + schunk * 8 + 4);
            float4 e0 = *(const float4*)(beta + kb + schunk * 8);
            float4 e1 = *(const float4*)(beta + kb + schunk * 8 + 4);
            short8_t o;
            o[0] = f2bf((v0.x - mu) * rs * g0.x + e0.x);
            o[1] = f2bf((v0.y - mu) * rs * g0.y + e0.y);
            o[2] = f2bf((v0.z - mu) * rs * g0.z + e0.z);
            o[3] = f2bf((v0.w - mu) * rs * g0.w + e0.w);
            o[4] = f2bf((v1.x - mu) * rs * g1.x + e1.x);
            o[5] = f2bf((v1.y - mu) * rs * g1.y + e1.y);
            o[6] = f2bf((v1.z - mu) * rs * g1.z + e1.z);
            o[7] = f2bf((v1.w - mu) * rs * g1.w + e1.w);
            int c = schunk ^ (srow & 7);
            *(short8_t*)&s_xn[srow * BK + c * 8] = o;
        }
        __syncthreads();
#pragma unroll
        for (int kk = 0; kk < BK; kk += 32) {
            int kcol = kk + kgrp * 8;
            int ch = (kcol >> 3) ^ (arow & 7);
            short8_t a = *(const short8_t*)&s_xn[arow * BK + ch * 8];
#pragma unroll
            for (int nt = 0; nt < 16; nt++) {
                int hcol = wh * 256 + nt * 16 + (lane & 15);
                const short* bp = Wd + (size_t)hcol * DD + kb + kcol;
                short8_t b = *(const short8_t*)bp;
                acc[nt] = __builtin_amdgcn_mfma_f32_16x16x32_bf16(a, b, acc[nt], 0, 0, 0);
            }
        }
        __syncthreads();
    }

    // epilogue: +b_down, ReLU, bf16 -> hid
    {
        int coln  = lane & 15;
        int rbase = wm * 16 + (lane >> 4) * 4;
#pragma unroll
        for (int nt = 0; nt < 16; nt++) {
            int h = wh * 256 + nt * 16 + coln;
            float bd = b_down[h];
#pragma unroll
            for (int j = 0; j < 4; j++) {
                float v = acc[nt][j] + bd;
                v = v > 0.f ? v : 0.f;
                int row = rbase + j;
                hid[(size_t)(tok0 + row) * HH + h] = f2bf(v);
            }
        }
    }
}

// ---------------- up-proj + bias + residual -> out fp32 ----------------
__global__ __launch_bounds__(512, 2) void k_up_res(
    const float* __restrict__ x, const short* __restrict__ hid,
    const short* __restrict__ Wu,   // bf16 [D][H], K(=h) contiguous
    const float* __restrict__ b_up, float* __restrict__ out)
{
    __shared__ __align__(16) short s_h[MT * BK];

    const int tid  = threadIdx.x;
    const int lane = tid & 63;
    const int w    = tid >> 6;
    const int tok0 = blockIdx.x * MT;
    const int wm = w >> 1, wd = w & 1;
    const int srow = tid >> 3, schunk = tid & 7;
    const int arow = wm * 16 + (lane & 15);
    const int kgrp = lane >> 4;

    for (int pass = 0; pass < 4; pass++) {
        int dbase = pass * 512 + wd * 256;
        f32x4 acc[16];
#pragma unroll
        for (int i = 0; i < 16; i++) acc[i] = (f32x4){0.f, 0.f, 0.f, 0.f};

        for (int kb = 0; kb < HH; kb += BK) {
            // stage hidden tile (bf16, swizzled)
            short8_t hv = *(const short8_t*)(hid + (size_t)(tok0 + srow) * HH + kb + schunk * 8);
            int c = schunk ^ (srow & 7);
            *(short8_t*)&s_h[srow * BK + c * 8] = hv;
            __syncthreads();
#pragma unroll
            for (int kk = 0; kk < BK; kk += 32) {
                int kcol = kk + kgrp * 8;
                int ch = (kcol >> 3) ^ (arow & 7);
                short8_t a = *(const short8_t*)&s_h[arow * BK + ch * 8];
#pragma unroll
                for (int nt = 0; nt < 16; nt++) {
                    int d = dbase + nt * 16 + (lane & 15);
                    const short* bp = Wu + (size_t)d * HH + kb + kcol;
                    short8_t b = *(const short8_t*)bp;
                    acc[nt] = __builtin_amdgcn_mfma_f32_16x16x32_bf16(a, b, acc[nt], 0, 0, 0);
                }
            }
            __syncthreads();
        }

        // epilogue: out = x + b_up + acc
        int coln  = lane & 15;
        int rbase = wm * 16 + (lane >> 4) * 4;
#pragma unroll
        for (int nt = 0; nt < 16; nt++) {
            int d = dbase + nt * 16 + coln;
            float bu = b_up[d];
#pragma unroll
            for (int j = 0; j < 4; j++) {
                int row = rbase + j;
                size_t idx = (size_t)(tok0 + row) * DD + d;
                out[idx] = x[idx] + bu + acc[nt][j];
            }
        }
    }
}

extern "C" void kernel_launch(void* const* d_in, const int* in_sizes, int n_in,
                              void* d_out, int out_size, void* d_ws, size_t ws_size,
                              hipStream_t stream) {
    const float* x     = (const float*)d_in[0];
    const float* gamma = (const float*)d_in[1];
    const float* beta  = (const float*)d_in[2];
    const float* Wd_f  = (const float*)d_in[3];  // [H, D]
    const float* bd    = (const float*)d_in[4];
    const float* Wu_f  = (const float*)d_in[5];  // [D, H]
    const float* bu    = (const float*)d_in[6];

    short* Wd  = (short*)d_ws;                 // 1048576 bf16 = 2 MB
    short* Wu  = Wd + (size_t)HH * DD;         // 2 MB
    short* hid = Wu + (size_t)DD * HH;         // 16384*512 bf16 = 16 MB

    k_cvt<<<1024, 256, 0, stream>>>(Wd_f, Wu_f, Wd, Wu);
    k_ln_down<<<NTOK / MT, 512, 0, stream>>>(x, gamma, beta, bd, Wd, hid);
    k_up_res<<<NTOK / MT, 512, 0, stream>>>(x, hid, Wu, bu, (float*)d_out);
}

// Round 2
// 198.017 us; speedup vs baseline: 3.2716x; 3.2716x over previous
//
#include <hip/hip_runtime.h>

#define DD 2048
#define HH 512
#define NTOK 16384

typedef __attribute__((ext_vector_type(8))) short short8_t;
typedef __attribute__((ext_vector_type(4))) short short4_t;
typedef __attribute__((ext_vector_type(4))) float f32x4;

static __device__ __forceinline__ short f2bf(float f) {
    union { float f; unsigned u; } v; v.f = f;
    unsigned r = (v.u + 0x7fffu + ((v.u >> 16) & 1u)) >> 16;
    return (short)r;
}

// async global->LDS, 16B per lane. lds base must be wave-uniform; HW adds lane*16.
static __device__ __forceinline__ void gl16(const short* g, short* l) {
    __builtin_amdgcn_global_load_lds(
        (const __attribute__((address_space(1))) unsigned int*)g,
        (__attribute__((address_space(3))) unsigned int*)l, 16, 0, 0);
}

// ---- prep: Wg = Wd * gamma (bf16), c1 = sum_k gamma*Wd, c2 = sum_k beta*Wd ----
__global__ __launch_bounds__(256) void k_cvtd(const float* __restrict__ Wd,
                                              const float* __restrict__ g,
                                              const float* __restrict__ be,
                                              short* __restrict__ Wg,
                                              float* __restrict__ c1,
                                              float* __restrict__ c2) {
    int w = threadIdx.x >> 6, lane = threadIdx.x & 63;
    int h = blockIdx.x * 4 + w;
    const float* wr = Wd + (size_t)h * DD;
    float s1 = 0.f, s2 = 0.f;
    for (int i = 0; i < 8; i++) {
        int col = i * 256 + lane * 4;
        float4 wv = *(const float4*)(wr + col);
        float4 gv = *(const float4*)(g + col);
        float4 bv = *(const float4*)(be + col);
        s1 += gv.x * wv.x + gv.y * wv.y + gv.z * wv.z + gv.w * wv.w;
        s2 += bv.x * wv.x + bv.y * wv.y + bv.z * wv.z + bv.w * wv.w;
        short4_t o;
        o[0] = f2bf(wv.x * gv.x); o[1] = f2bf(wv.y * gv.y);
        o[2] = f2bf(wv.z * gv.z); o[3] = f2bf(wv.w * gv.w);
        *(short4_t*)(Wg + (size_t)h * DD + col) = o;
    }
    for (int m = 1; m < 64; m <<= 1) { s1 += __shfl_xor(s1, m); s2 += __shfl_xor(s2, m); }
    if (lane == 0) { c1[h] = s1; c2[h] = s2; }
}

// ---- prep: Wu fp32 -> bf16 ----
__global__ __launch_bounds__(256) void k_cvtu(const float* __restrict__ Wu,
                                              short* __restrict__ Wub) {
    int i = (blockIdx.x * 256 + threadIdx.x) * 4;
    float4 v = *(const float4*)(Wu + i);
    short4_t o;
    o[0] = f2bf(v.x); o[1] = f2bf(v.y); o[2] = f2bf(v.z); o[3] = f2bf(v.w);
    *(short4_t*)(Wub + i) = o;
}

// ---- GEMM1: hid = relu(rs*(x_bf16 . Wg^T - mu*c1) + c2 + bd), stats fused ----
__global__ __launch_bounds__(256, 3) void k_down(
    const float* __restrict__ x, const short* __restrict__ Wg,
    const float* __restrict__ c1, const float* __restrict__ c2,
    const float* __restrict__ bd, short* __restrict__ hid)
{
    __shared__ __align__(16) short s_a[128 * 64];
    __shared__ __align__(16) short s_b[128 * 64];
    __shared__ float s_sum[128][8];
    __shared__ float s_sq[128][8];
    __shared__ float s_mu[128], s_rs[128];

    // bijective XCD swizzle, nwg=512 (div by 8); n-major, m fastest
    int bid = blockIdx.x;
    int nb = (bid & 7) * 64 + (bid >> 3);
    const int m0 = (nb & 127) * 128;
    const int n0 = (nb >> 7) * 128;

    const int tid = threadIdx.x;
    const int lane = tid & 63;
    const int w = tid >> 6;
    const int wm = w >> 1, wn = w & 1;   // 2x2 waves, 64x64 each
    const int ar = tid >> 3;             // A-stage base row (rows ar+32*i)
    const int ac = tid & 7;              // A-stage k-chunk

    float psum[4] = {0.f, 0.f, 0.f, 0.f}, psq[4] = {0.f, 0.f, 0.f, 0.f};
    f32x4 acc[4][4];
#pragma unroll
    for (int i = 0; i < 4; i++)
#pragma unroll
        for (int j = 0; j < 4; j++) acc[i][j] = (f32x4){0.f, 0.f, 0.f, 0.f};

    for (int kb = 0; kb < DD; kb += 64) {
        // B tile via global_load_lds, source pre-swizzled
#pragma unroll
        for (int i = 0; i < 4; i++) {
            int ch = i * 256 + w * 64 + lane;
            int r = ch >> 3, c = ch & 7;
            const short* src = Wg + (size_t)(n0 + r) * DD + kb + ((c ^ (r & 7)) << 3);
            gl16(src, s_b + (size_t)(i * 256 + w * 64) * 8);
        }
        // A tile: reg-stage x f32 -> bf16, swizzled ds_write, accumulate LN stats
#pragma unroll
        for (int i = 0; i < 4; i++) {
            int r = i * 32 + ar;
            const float* p = x + (size_t)(m0 + r) * DD + kb + ac * 8;
            float4 v0 = *(const float4*)p;
            float4 v1 = *(const float4*)(p + 4);
            psum[i] += v0.x + v0.y + v0.z + v0.w + v1.x + v1.y + v1.z + v1.w;
            psq[i]  += v0.x * v0.x + v0.y * v0.y + v0.z * v0.z + v0.w * v0.w
                     + v1.x * v1.x + v1.y * v1.y + v1.z * v1.z + v1.w * v1.w;
            short8_t o;
            o[0] = f2bf(v0.x); o[1] = f2bf(v0.y); o[2] = f2bf(v0.z); o[3] = f2bf(v0.w);
            o[4] = f2bf(v1.x); o[5] = f2bf(v1.y); o[6] = f2bf(v1.z); o[7] = f2bf(v1.w);
            *(short8_t*)&s_a[r * 64 + ((ac ^ (r & 7)) << 3)] = o;
        }
        __syncthreads();
#pragma unroll
        for (int kk = 0; kk < 2; kk++) {
            int kc = kk * 4 + (lane >> 4);
            short8_t af[4], bfr[4];
#pragma unroll
            for (int mi = 0; mi < 4; mi++) {
                int rr = wm * 64 + mi * 16 + (lane & 15);
                af[mi] = *(const short8_t*)&s_a[rr * 64 + ((kc ^ (rr & 7)) << 3)];
            }
#pragma unroll
            for (int ni = 0; ni < 4; ni++) {
                int rr = wn * 64 + ni * 16 + (lane & 15);
                bfr[ni] = *(const short8_t*)&s_b[rr * 64 + ((kc ^ (rr & 7)) << 3)];
            }
#pragma unroll
            for (int mi = 0; mi < 4; mi++)
#pragma unroll
                for (int ni = 0; ni < 4; ni++)
                    acc[mi][ni] = __builtin_amdgcn_mfma_f32_16x16x32_bf16(
                        af[mi], bfr[ni], acc[mi][ni], 0, 0, 0);
        }
        __syncthreads();
    }

    // LN stats reduce (8 partials per row)
#pragma unroll
    for (int i = 0; i < 4; i++) {
        s_sum[i * 32 + ar][ac] = psum[i];
        s_sq[i * 32 + ar][ac]  = psq[i];
    }
    __syncthreads();
    if (tid < 128) {
        float s = 0.f, q = 0.f;
#pragma unroll
        for (int c = 0; c < 8; c++) { s += s_sum[tid][c]; q += s_sq[tid][c]; }
        float mu = s * (1.f / DD);
        float var = q * (1.f / DD) - mu * mu;
        s_mu[tid] = mu;
        s_rs[tid] = rsqrtf(var + 1e-5f);
    }
    __syncthreads();

    // epilogue
    const int coln = lane & 15;
#pragma unroll
    for (int ni = 0; ni < 4; ni++) {
        int h = n0 + wn * 64 + ni * 16 + coln;
        float C1 = c1[h];
        float C2 = c2[h] + bd[h];
#pragma unroll
        for (int mi = 0; mi < 4; mi++) {
            int rbase = wm * 64 + mi * 16 + ((lane >> 4) << 2);
#pragma unroll
            for (int j = 0; j < 4; j++) {
                int r = rbase + j;
                float v = s_rs[r] * (acc[mi][ni][j] - s_mu[r] * C1) + C2;
                v = v > 0.f ? v : 0.f;
                hid[(size_t)(m0 + r) * HH + h] = f2bf(v);
            }
        }
    }
}

// ---- GEMM2: out = x + bu + hid . Wu^T ----
__global__ __launch_bounds__(256, 4) void k_up(
    const float* __restrict__ x, const short* __restrict__ hid,
    const short* __restrict__ Wub, const float* __restrict__ bu,
    float* __restrict__ out)
{
    __shared__ __align__(16) short s_a[128 * 64];
    __shared__ __align__(16) short s_b[128 * 64];

    // nwg=2048 (div by 8); n-major, m fastest
    int bid = blockIdx.x;
    int nb = (bid & 7) * 256 + (bid >> 3);
    const int m0 = (nb & 127) * 128;
    const int n0 = (nb >> 7) * 128;

    const int tid = threadIdx.x;
    const int lane = tid & 63;
    const int w = tid >> 6;
    const int wm = w >> 1, wn = w & 1;

    f32x4 acc[4][4];
#pragma unroll
    for (int i = 0; i < 4; i++)
#pragma unroll
        for (int j = 0; j < 4; j++) acc[i][j] = (f32x4){0.f, 0.f, 0.f, 0.f};

    for (int kb = 0; kb < HH; kb += 64) {
#pragma unroll
        for (int i = 0; i < 4; i++) {
            int ch = i * 256 + w * 64 + lane;
            int r = ch >> 3, c = ch & 7;
            const short* srcA = hid + (size_t)(m0 + r) * HH + kb + ((c ^ (r & 7)) << 3);
            const short* srcB = Wub + (size_t)(n0 + r) * HH + kb + ((c ^ (r & 7)) << 3);
            gl16(srcA, s_a + (size_t)(i * 256 + w * 64) * 8);
            gl16(srcB, s_b + (size_t)(i * 256 + w * 64) * 8);
        }
        __syncthreads();
#pragma unroll
        for (int kk = 0; kk < 2; kk++) {
            int kc = kk * 4 + (lane >> 4);
            short8_t af[4], bfr[4];
#pragma unroll
            for (int mi = 0; mi < 4; mi++) {
                int rr = wm * 64 + mi * 16 + (lane & 15);
                af[mi] = *(const short8_t*)&s_a[rr * 64 + ((kc ^ (rr & 7)) << 3)];
            }
#pragma unroll
            for (int ni = 0; ni < 4; ni++) {
                int rr = wn * 64 + ni * 16 + (lane & 15);
                bfr[ni] = *(const short8_t*)&s_b[rr * 64 + ((kc ^ (rr & 7)) << 3)];
            }
#pragma unroll
            for (int mi = 0; mi < 4; mi++)
#pragma unroll
                for (int ni = 0; ni < 4; ni++)
                    acc[mi][ni] = __builtin_amdgcn_mfma_f32_16x16x32_bf16(
                        af[mi], bfr[ni], acc[mi][ni], 0, 0, 0);
        }
        __syncthreads();
    }

    const int coln = lane & 15;
#pragma unroll
    for (int ni = 0; ni < 4; ni++) {
        int d = n0 + wn * 64 + ni * 16 + coln;
        float B = bu[d];
#pragma unroll
        for (int mi = 0; mi < 4; mi++) {
            int rbase = wm * 64 + mi * 16 + ((lane >> 4) << 2);
#pragma unroll
            for (int j = 0; j < 4; j++) {
                int r = rbase + j;
                size_t idx = (size_t)(m0 + r) * DD + d;
                out[idx] = x[idx] + B + acc[mi][ni][j];
            }
        }
    }
}

extern "C" void kernel_launch(void* const* d_in, const int* in_sizes, int n_in,
                              void* d_out, int out_size, void* d_ws, size_t ws_size,
                              hipStream_t stream) {
    const float* x     = (const float*)d_in[0];
    const float* gamma = (const float*)d_in[1];
    const float* beta  = (const float*)d_in[2];
    const float* Wd_f  = (const float*)d_in[3];  // [H, D]
    const float* bd    = (const float*)d_in[4];
    const float* Wu_f  = (const float*)d_in[5];  // [D, H]
    const float* bu    = (const float*)d_in[6];

    short* Wg  = (short*)d_ws;                         // 2 MB bf16 [H][D] (= Wd*gamma)
    short* Wub = Wg + (size_t)HH * DD;                 // 2 MB bf16 [D][H]
    float* c1  = (float*)(Wub + (size_t)DD * HH);      // 2 KB
    float* c2  = c1 + HH;                              // 2 KB
    short* hid = (short*)(c2 + HH);                    // 16 MB bf16 [NTOK][H]

    k_cvtd<<<HH / 4, 256, 0, stream>>>(Wd_f, gamma, beta, Wg, c1, c2);
    k_cvtu<<<(DD * HH) / 1024, 256, 0, stream>>>(Wu_f, Wub);
    k_down<<<(NTOK / 128) * (HH / 128), 256, 0, stream>>>(x, Wg, c1, c2, bd, hid);
    k_up<<<(NTOK / 128) * (DD / 128), 256, 0, stream>>>(x, hid, Wub, bu, (float*)d_out);
}

// Round 3
// 142.480 us; speedup vs baseline: 4.5468x; 1.3898x over previous
//
#include <hip/hip_runtime.h>

#define DD 2048
#define HH 512
#define NTOK 16384

typedef __attribute__((ext_vector_type(8))) short short8_t;
typedef __attribute__((ext_vector_type(4))) short short4_t;
typedef __attribute__((ext_vector_type(4))) float f32x4;

static __device__ __forceinline__ short f2bf(float f) {
    union { float f; unsigned u; } v; v.f = f;
    unsigned r = (v.u + 0x7fffu + ((v.u >> 16) & 1u)) >> 16;
    return (short)r;
}

// async global->LDS, 16B per lane. lds base wave-uniform; HW adds lane*16.
static __device__ __forceinline__ void gl16(const short* g, short* l) {
    __builtin_amdgcn_global_load_lds(
        (const __attribute__((address_space(1))) unsigned int*)g,
        (__attribute__((address_space(3))) unsigned int*)l, 16, 0, 0);
}

// ---- prep: Wg = Wd*gamma bf16, c1=sum Wg, c2=sum beta*Wd; Wu -> bf16 ----
__global__ __launch_bounds__(256) void k_wprep(
    const float* __restrict__ Wd, const float* __restrict__ g,
    const float* __restrict__ be, const float* __restrict__ Wu,
    short* __restrict__ Wg, short* __restrict__ Wub,
    float* __restrict__ c1, float* __restrict__ c2)
{
    int bid = blockIdx.x;
    if (bid < 128) {
        int w = threadIdx.x >> 6, lane = threadIdx.x & 63;
        int h = bid * 4 + w;
        const float* wr = Wd + (size_t)h * DD;
        float s1 = 0.f, s2 = 0.f;
        for (int i = 0; i < 8; i++) {
            int col = i * 256 + lane * 4;
            float4 wv = *(const float4*)(wr + col);
            float4 gv = *(const float4*)(g + col);
            float4 bv = *(const float4*)(be + col);
            s1 += gv.x * wv.x + gv.y * wv.y + gv.z * wv.z + gv.w * wv.w;
            s2 += bv.x * wv.x + bv.y * wv.y + bv.z * wv.z + bv.w * wv.w;
            short4_t o;
            o[0] = f2bf(wv.x * gv.x); o[1] = f2bf(wv.y * gv.y);
            o[2] = f2bf(wv.z * gv.z); o[3] = f2bf(wv.w * gv.w);
            *(short4_t*)(Wg + (size_t)h * DD + col) = o;
        }
        for (int m = 1; m < 64; m <<= 1) { s1 += __shfl_xor(s1, m); s2 += __shfl_xor(s2, m); }
        if (lane == 0) { c1[h] = s1; c2[h] = s2; }
    } else {
        int b = bid - 128;  // 0..255
        for (int r = 0; r < 4; r++) {
            int i = (b * 4 + r) * 1024 + threadIdx.x * 4;
            float4 v = *(const float4*)(Wu + i);
            short4_t o;
            o[0] = f2bf(v.x); o[1] = f2bf(v.y); o[2] = f2bf(v.z); o[3] = f2bf(v.w);
            *(short4_t*)(Wub + i) = o;
        }
    }
}

// ---- fused: LN + down + ReLU + up + residual, one block per 64 tokens ----
__global__ __launch_bounds__(512, 2) void k_fused(
    const float* __restrict__ x, const short* __restrict__ Wg,
    const float* __restrict__ c1, const float* __restrict__ c2,
    const float* __restrict__ bd, const short* __restrict__ Wub,
    const float* __restrict__ bu, float* __restrict__ out)
{
    // LDS map (bytes):
    // phase1: B1 dbuf [0,131072), A1 dbuf [131072,147456), stats [147456,152064)
    // phase2: Hld(hid) [0,65536), B2 dbuf [65536,131072)
    __shared__ __align__(16) char smem[152064];
    short* B1   = (short*)smem;               // [2][512*64] shorts
    short* A1   = (short*)(smem + 131072);    // [2][64*64]
    float* s_sum = (float*)(smem + 147456);   // [64][8]
    float* s_sq  = (float*)(smem + 149504);   // [64][8]
    float* s_mu  = (float*)(smem + 151552);   // [64]
    float* s_rs  = (float*)(smem + 151808);   // [64]
    short* Hld  = (short*)smem;               // [64][512] swizzled
    short* B2   = (short*)(smem + 65536);     // [2][256*64]

    const int tid  = threadIdx.x;
    const int lane = tid & 63;
    const int w    = tid >> 6;     // wave 0..7
    const int l15  = lane & 15;
    const int rg   = lane >> 4;    // 0..3
    const int m0   = blockIdx.x * 64;

    // A-staging identity: thread -> (row 0..63, 8-elem chunk 0..7)
    const int srow = tid >> 3;
    const int sc   = tid & 7;
    const float* xrow = x + (size_t)(m0 + srow) * DD + sc * 8;

    float psum = 0.f, psq = 0.f;
    float4 xv0, xv1;

    auto stageB1 = [&](short* buf, int kb) {
#pragma unroll
        for (int i = 0; i < 8; i++) {
            int ch = i * 512 + tid;
            int r = ch >> 3, c = ch & 7;
            gl16(Wg + (size_t)r * DD + kb + ((c ^ (r & 7)) << 3),
                 buf + (i * 512 + (w << 6)) * 8);
        }
    };
    auto loadA = [&](int kb) {
        xv0 = *(const float4*)(xrow + kb);
        xv1 = *(const float4*)(xrow + kb + 4);
    };
    auto writeA = [&](short* buf) {
        psum += xv0.x + xv0.y + xv0.z + xv0.w + xv1.x + xv1.y + xv1.z + xv1.w;
        psq  += xv0.x * xv0.x + xv0.y * xv0.y + xv0.z * xv0.z + xv0.w * xv0.w
              + xv1.x * xv1.x + xv1.y * xv1.y + xv1.z * xv1.z + xv1.w * xv1.w;
        short8_t o;
        o[0] = f2bf(xv0.x); o[1] = f2bf(xv0.y); o[2] = f2bf(xv0.z); o[3] = f2bf(xv0.w);
        o[4] = f2bf(xv1.x); o[5] = f2bf(xv1.y); o[6] = f2bf(xv1.z); o[7] = f2bf(xv1.w);
        *(short8_t*)(buf + srow * 64 + ((sc ^ (srow & 7)) << 3)) = o;
    };

    // ---------------- phase 1: hid = LN(x) @ Wg^T (+relu, in epilogue) ----
    f32x4 acc[4][4];
#pragma unroll
    for (int i = 0; i < 4; i++)
#pragma unroll
        for (int j = 0; j < 4; j++) acc[i][j] = (f32x4){0.f, 0.f, 0.f, 0.f};

    stageB1(B1, 0);
    loadA(0);
    writeA(A1);
    __syncthreads();

    int cur = 0;
    for (int t = 0; t < 32; t++) {
        int nxt = cur ^ 1;
        if (t < 31) {
            stageB1(B1 + nxt * 32768, (t + 1) * 64);
            loadA((t + 1) * 64);
        }
        const short* bufA = A1 + cur * 4096;
        const short* bufB = B1 + cur * 32768;
#pragma unroll
        for (int kk = 0; kk < 2; kk++) {
            int kc = kk * 4 + rg;
            short8_t af[4], bf[4];
#pragma unroll
            for (int mi = 0; mi < 4; mi++) {
                int rr = mi * 16 + l15;
                af[mi] = *(const short8_t*)(bufA + rr * 64 + ((kc ^ (rr & 7)) << 3));
            }
#pragma unroll
            for (int ni = 0; ni < 4; ni++) {
                int rr = (w << 6) + ni * 16 + l15;
                bf[ni] = *(const short8_t*)(bufB + rr * 64 + ((kc ^ (rr & 7)) << 3));
            }
#pragma unroll
            for (int mi = 0; mi < 4; mi++)
#pragma unroll
                for (int ni = 0; ni < 4; ni++)
                    acc[mi][ni] = __builtin_amdgcn_mfma_f32_16x16x32_bf16(
                        af[mi], bf[ni], acc[mi][ni], 0, 0, 0);
        }
        if (t < 31) writeA(A1 + nxt * 4096);
        __syncthreads();
        cur = nxt;
    }

    // LN stats reduce
    s_sum[(srow << 3) + sc] = psum;
    s_sq[(srow << 3) + sc]  = psq;
    __syncthreads();
    if (tid < 64) {
        float s = 0.f, q = 0.f;
#pragma unroll
        for (int c = 0; c < 8; c++) { s += s_sum[(tid << 3) + c]; q += s_sq[(tid << 3) + c]; }
        float mu = s * (1.f / DD);
        float var = q * (1.f / DD) - mu * mu;
        s_mu[tid] = mu;
        s_rs[tid] = rsqrtf(var + 1e-5f);
    }
    __syncthreads();

    // phase-1 epilogue: LN-affine + bias + relu -> hid in LDS (swizzled bf16)
#pragma unroll
    for (int ni = 0; ni < 4; ni++) {
        int h = (w << 6) + ni * 16 + l15;
        float C1 = c1[h];
        float C2 = c2[h] + bd[h];
#pragma unroll
        for (int mi = 0; mi < 4; mi++) {
#pragma unroll
            for (int j = 0; j < 4; j++) {
                int row = mi * 16 + rg * 4 + j;
                float v = s_rs[row] * (acc[mi][ni][j] - s_mu[row] * C1) + C2;
                v = v > 0.f ? v : 0.f;
                Hld[row * 512 + (((h >> 3) ^ (row & 7)) << 3) + (h & 7)] = f2bf(v);
            }
        }
    }

    auto stageB2 = [&](short* buf, int dp, int kb) {
#pragma unroll
        for (int i = 0; i < 4; i++) {
            int ch = i * 512 + tid;
            int r = ch >> 3, c = ch & 7;
            gl16(Wub + (size_t)(dp * 256 + r) * HH + kb + ((c ^ (r & 7)) << 3),
                 buf + (i * 512 + (w << 6)) * 8);
        }
    };

    stageB2(B2, 0, 0);   // B1[1] region: safe, last read 2 barriers ago
    __syncthreads();     // drains hid ds_writes + B2 gl16

    // ---------------- phase 2: out = x + bu + hid @ Wu^T ----
    f32x4 acc2[4][2];
#pragma unroll
    for (int i = 0; i < 4; i++)
#pragma unroll
        for (int j = 0; j < 2; j++) acc2[i][j] = (f32x4){0.f, 0.f, 0.f, 0.f};

    cur = 0;
    for (int s = 0; s < 64; s++) {
        int nxt = cur ^ 1;
        if (s < 63) stageB2(B2 + nxt * 16384, (s + 1) >> 3, ((s + 1) & 7) * 64);
        int ks = s & 7;
        const short* bufB = B2 + cur * 16384;
#pragma unroll
        for (int kk = 0; kk < 2; kk++) {
            int kcA = (ks << 3) + kk * 4 + rg;   // chunk 0..63 in hid row
            int kcB = kk * 4 + rg;
            short8_t af[4], bf2[2];
#pragma unroll
            for (int mi = 0; mi < 4; mi++) {
                int rr = mi * 16 + l15;
                af[mi] = *(const short8_t*)(Hld + rr * 512 + ((kcA ^ (rr & 7)) << 3));
            }
#pragma unroll
            for (int ni = 0; ni < 2; ni++) {
                int rr = (w << 5) + ni * 16 + l15;
                bf2[ni] = *(const short8_t*)(bufB + rr * 64 + ((kcB ^ (rr & 7)) << 3));
            }
#pragma unroll
            for (int mi = 0; mi < 4; mi++)
#pragma unroll
                for (int ni = 0; ni < 2; ni++)
                    acc2[mi][ni] = __builtin_amdgcn_mfma_f32_16x16x32_bf16(
                        af[mi], bf2[ni], acc2[mi][ni], 0, 0, 0);
        }
        if (ks == 7) {
            int dp = s >> 3;
#pragma unroll
            for (int ni = 0; ni < 2; ni++) {
                int d = dp * 256 + (w << 5) + ni * 16 + l15;
                float B = bu[d];
#pragma unroll
                for (int mi = 0; mi < 4; mi++) {
#pragma unroll
                    for (int j = 0; j < 4; j++) {
                        int row = mi * 16 + rg * 4 + j;
                        size_t idx = (size_t)(m0 + row) * DD + d;
                        out[idx] = x[idx] + B + acc2[mi][ni][j];
                        acc2[mi][ni][j] = 0.f;
                    }
                }
            }
        }
        __syncthreads();
        cur = nxt;
    }
}

extern "C" void kernel_launch(void* const* d_in, const int* in_sizes, int n_in,
                              void* d_out, int out_size, void* d_ws, size_t ws_size,
                              hipStream_t stream) {
    const float* x     = (const float*)d_in[0];
    const float* gamma = (const float*)d_in[1];
    const float* beta  = (const float*)d_in[2];
    const float* Wd_f  = (const float*)d_in[3];  // [H, D]
    const float* bd    = (const float*)d_in[4];
    const float* Wu_f  = (const float*)d_in[5];  // [D, H]
    const float* bu    = (const float*)d_in[6];

    short* Wg  = (short*)d_ws;                     // 2 MB bf16 [H][D] (Wd*gamma)
    short* Wub = Wg + (size_t)HH * DD;             // 2 MB bf16 [D][H]
    float* c1  = (float*)(Wub + (size_t)DD * HH);  // 2 KB
    float* c2  = c1 + HH;                          // 2 KB

    k_wprep<<<384, 256, 0, stream>>>(Wd_f, gamma, beta, Wu_f, Wg, Wub, c1, c2);
    k_fused<<<NTOK / 64, 512, 0, stream>>>(x, Wg, c1, c2, bd, Wub, bu, (float*)d_out);
}